// Round 7
// baseline (2163.470 us; speedup 1.0000x reference)
//
#include <hip/hip_runtime.h>
#include <hip/hip_bf16.h>
#include <math.h>

#define H       256
#define TB      32      // samples per workgroup
#define NT      512     // threads per workgroup (8 waves, one 32-row group each)
#define NSTEPS  32
#define XS      264     // bf16 elems per activation row: 528B
#define DS1     260     // bf16 elems per d1 row: 520B

typedef __attribute__((ext_vector_type(8)))  short short8v;   // MFMA A/B frag: 8 bf16
typedef __attribute__((ext_vector_type(16))) float f32x16;    // MFMA C/D frag

// tanh via v_exp + v_rcp: ~5 ops, 2 trans. No clamp needed:
//  x>>0: e=inf -> rcp(inf)=0 -> h=1 ;  x<<0: e=0 -> rcp(1)=1 -> h=-1.
__device__ __forceinline__ float fast_tanh(float x) {
    float e;
    asm("v_exp_f32 %0, %1" : "=v"(e) : "v"(x * 2.8853900817779268f)); // 2^(2x*log2e)
    return fmaf(-2.0f, __builtin_amdgcn_rcpf(e + 1.0f), 1.0f);
}

// pack 2 fp32 -> 1 u32 of 2 bf16, RNE (v_cvt_pk_bf16_f32)
__device__ __forceinline__ unsigned pk2(float lo, float hi) {
    __hip_bfloat162 h2 = __float22bfloat162_rn(make_float2(lo, hi));
    unsigned u; __builtin_memcpy(&u, &h2, 4);
    return u;
}
// fp32 -> bf16 bits, round-to-nearest-even (scalar, for the pre-pass)
__device__ __forceinline__ unsigned short f2b(float x) {
    unsigned u = __float_as_uint(x);
    u += 0x7FFFu + ((u >> 16) & 1u);
    return (unsigned short)(u >> 16);
}
__device__ __forceinline__ float b2f(unsigned short h) {
    return __uint_as_float(((unsigned)h) << 16);
}

// ---- pre-pass: fp32 W2,W3 -> bf16 row-major + transposed copies in d_ws ----
// ws layout (bf16 elems): W2b[0,64K) W3b[64K,128K) W2Tb[128K,192K) W3Tb[192K,256K)
__global__ void convert_w(const float* __restrict__ W2, const float* __restrict__ W3,
                          unsigned short* __restrict__ wsb) {
    int t = blockIdx.x * blockDim.x + threadIdx.x;   // 0..65535
    int i = t >> 8, j = t & 255;
    float w2 = W2[t], w3 = W3[t];
    wsb[t]                         = f2b(w2);
    wsb[65536 + t]                 = f2b(w3);
    wsb[131072 + (j << 8) + i]     = f2b(w2);   // W2T[j][i] = W2[i][j]
    wsb[196608 + (j << 8) + i]     = f2b(w3);
}

// ---- forced register burst: 16 x global_load_dwordx4 as inline asm.
// asm volatile outputs are 16 live 128-bit tuples the allocator cannot split,
// sink, or rematerialize -> the scheduler CANNOT re-serialize the loads (the
// round-5/6 failure where the backend squeezed into the 64-VGPR tier).
// One base address + offset immediates (kc*32 bytes, max 480, fits 13-bit).
#define GL(dst, base, OFFB)                                                    \
    asm volatile("global_load_dwordx4 %0, %1, off offset:" #OFFB               \
                 : "=v"(dst) : "v"(base));

#define LOADW(w, base)                                                         \
    GL(w[0],  base, 0)   GL(w[1],  base, 32)  GL(w[2],  base, 64)              \
    GL(w[3],  base, 96)  GL(w[4],  base, 128) GL(w[5],  base, 160)             \
    GL(w[6],  base, 192) GL(w[7],  base, 224) GL(w[8],  base, 256)             \
    GL(w[9],  base, 288) GL(w[10], base, 320) GL(w[11], base, 352)             \
    GL(w[12], base, 384) GL(w[13], base, 416) GL(w[14], base, 448)             \
    GL(w[15], base, 480)                                                       \
    asm volatile("s_waitcnt vmcnt(0)" ::: "memory");                           \
    __builtin_amdgcn_sched_barrier(0);   /* rule #18: fence MFMA hoisting */

// single-accumulator MFMA chain over K=256 (16 steps); B from LDS
#define MFMA_CHAIN(WREG, XSRC, ACC)                                            \
    _Pragma("unroll")                                                          \
    for (int kc = 0; kc < 16; ++kc) {                                          \
        short8v b = *reinterpret_cast<const short8v*>(&XSRC[col][kc*16 + q*8]);\
        ACC = __builtin_amdgcn_mfma_f32_32x32x16_bf16(WREG[kc], b, ACC, 0, 0, 0); \
    }

__global__ __launch_bounds__(NT, 4)   // VGPR<=128 so 2 blocks/CU co-reside
void sympnet_mfma(const float* __restrict__ t_eval,
                  const float* __restrict__ state0,
                  const float* __restrict__ W1, const float* __restrict__ b1,
                  const float* __restrict__ b2, const float* __restrict__ b3,
                  const float* __restrict__ W4, const float* __restrict__ scale_p,
                  const short* __restrict__ W2b,  const short* __restrict__ W3b,
                  const short* __restrict__ W2Tb, const short* __restrict__ W3Tb,
                  float* __restrict__ out)
{
    __shared__ unsigned short Xa[TB][XS];
    __shared__ unsigned short Xb[TB][XS];
    __shared__ unsigned short D1[TB][DS1];   // (1 - h1^2) bf16
    __shared__ float sS[TB][4];
    __shared__ float gp[8][TB][4];           // per-row-group gradient partials
    __shared__ float sW1[H * 4];             // W1 rows (float4 each), L1 + B2 fold
    __shared__ float sB1[H], sB2[H], sB3[H], sW4[H];

    const int tid  = threadIdx.x;
    const int lane = tid & 63;
    const int wv   = tid >> 6;      // wave 0..7
    const int col  = lane & 31;     // MFMA lane&31 (M-row for A, sample for B/C)
    const int q    = lane >> 5;
    const int n0   = wv * 32;       // this wave's 32 output rows for every GEMM

    const float dt    = t_eval[1] - t_eval[0];
    const float scale = scale_p[0];
    const int   b0    = blockIdx.x * TB;

    // per-wave weight row base pointers (rows n0+col, k-slice q*8)
    const short* W2p  = W2b  + ((n0 + col) << 8) + q * 8;
    const short* W3p  = W3b  + ((n0 + col) << 8) + q * 8;
    const short* W3Tp = W3Tb + ((n0 + col) << 8) + q * 8;
    const short* W2Tp = W2Tb + ((n0 + col) << 8) + q * 8;

    if (tid < H) {
        reinterpret_cast<float4*>(sW1)[tid] = reinterpret_cast<const float4*>(W1)[tid];
        sB1[tid] = b1[tid];
        sB2[tid] = b2[tid];
        sB3[tid] = b3[tid];
        sW4[tid] = W4[tid];
    }
    if (tid < TB) {
        float4 s = reinterpret_cast<const float4*>(state0)[b0 + tid];
        sS[tid][0] = s.x; sS[tid][1] = s.y; sS[tid][2] = s.z; sS[tid][3] = s.w;
        reinterpret_cast<float4*>(out)[(size_t)(b0 + tid) * NSTEPS] = s;
    }
    __syncthreads();

    unsigned d2p[8];   // (1 - h2^2) packed bf16 pairs, in registers

    for (int t = 1; t < NSTEPS; ++t) {
        // ================= L1 (VALU): h1 = tanh(s @ W1^T + b1) -> Xa, D1
        {
            const int j0 = (tid & 31) * 8;        // 32 dim-groups of 8
            const int r0 = (tid >> 5) * 2;        // 16 slots x 2 rows = 32 samples
            float4 wvv[8];
            #pragma unroll
            for (int jj = 0; jj < 8; ++jj)
                wvv[jj] = reinterpret_cast<const float4*>(sW1)[j0 + jj];
            float bb[8];
            #pragma unroll
            for (int jj = 0; jj < 8; ++jj) bb[jj] = sB1[j0 + jj];
            #pragma unroll
            for (int ii = 0; ii < 2; ++ii) {
                float4 sv = *reinterpret_cast<const float4*>(&sS[r0 + ii][0]);
                float h[8], d[8];
                #pragma unroll
                for (int jj = 0; jj < 8; ++jj) {
                    float z = bb[jj] + sv.x * wvv[jj].x + sv.y * wvv[jj].y
                                     + sv.z * wvv[jj].z + sv.w * wvv[jj].w;
                    h[jj] = fast_tanh(z);
                    d[jj] = fmaf(-h[jj], h[jj], 1.0f);
                }
                *reinterpret_cast<uint2*>(&Xa[r0 + ii][j0]) =
                    make_uint2(pk2(h[0], h[1]), pk2(h[2], h[3]));
                *reinterpret_cast<uint2*>(&Xa[r0 + ii][j0 + 4]) =
                    make_uint2(pk2(h[4], h[5]), pk2(h[6], h[7]));
                *reinterpret_cast<uint2*>(&D1[r0 + ii][j0]) =
                    make_uint2(pk2(d[0], d[1]), pk2(d[2], d[3]));
                *reinterpret_cast<uint2*>(&D1[r0 + ii][j0 + 4]) =
                    make_uint2(pk2(d[4], d[5]), pk2(d[6], d[7]));
            }
        }
        __syncthreads();

        // ================= L2 (MFMA): h2 = tanh(W2 h1 + b2) -> Xb, d2p regs
        {
            short8v w[16];
            LOADW(w, W2p);
            f32x16 acc = {};
            MFMA_CHAIN(w, Xa, acc);
            #pragma unroll
            for (int g = 0; g < 4; ++g) {
                float4 bv = *reinterpret_cast<const float4*>(&sB2[n0 + 8*g + 4*q]);
                const float* bp = reinterpret_cast<const float*>(&bv);
                float h[4], d[4];
                #pragma unroll
                for (int rr = 0; rr < 4; ++rr) {
                    h[rr] = fast_tanh(acc[4*g + rr] + bp[rr]);
                    d[rr] = fmaf(-h[rr], h[rr], 1.0f);
                }
                d2p[2*g]     = pk2(d[0], d[1]);
                d2p[2*g + 1] = pk2(d[2], d[3]);
                *reinterpret_cast<uint2*>(&Xb[col][n0 + 8*g + 4*q]) =
                    make_uint2(pk2(h[0], h[1]), pk2(h[2], h[3]));
            }
        }
        __syncthreads();

        // ================= L3 (MFMA): u3 = W4 ⊙ (1 - tanh^2(W3 h2 + b3)) -> Xa
        {
            short8v w[16];
            LOADW(w, W3p);
            f32x16 acc = {};
            MFMA_CHAIN(w, Xb, acc);
            #pragma unroll
            for (int g = 0; g < 4; ++g) {
                float4 bv = *reinterpret_cast<const float4*>(&sB3[n0 + 8*g + 4*q]);
                float4 wv4 = *reinterpret_cast<const float4*>(&sW4[n0 + 8*g + 4*q]);
                const float* bp = reinterpret_cast<const float*>(&bv);
                const float* wp = reinterpret_cast<const float*>(&wv4);
                float u[4];
                #pragma unroll
                for (int rr = 0; rr < 4; ++rr) {
                    float h = fast_tanh(acc[4*g + rr] + bp[rr]);
                    u[rr] = wp[rr] * fmaf(-h, h, 1.0f);
                }
                *reinterpret_cast<uint2*>(&Xa[col][n0 + 8*g + 4*q]) =
                    make_uint2(pk2(u[0], u[1]), pk2(u[2], u[3]));
            }
        }
        __syncthreads();

        // ================= B1 (MFMA): u2 = (W3^T u3) ⊙ d2 -> Xb
        {
            short8v w[16];
            LOADW(w, W3Tp);
            f32x16 acc = {};
            MFMA_CHAIN(w, Xa, acc);
            #pragma unroll
            for (int g = 0; g < 4; ++g) {
                float dd[4] = { b2f((unsigned short)(d2p[2*g]   & 0xffffu)),
                                b2f((unsigned short)(d2p[2*g]   >> 16)),
                                b2f((unsigned short)(d2p[2*g+1] & 0xffffu)),
                                b2f((unsigned short)(d2p[2*g+1] >> 16)) };
                float u[4];
                #pragma unroll
                for (int rr = 0; rr < 4; ++rr)
                    u[rr] = acc[4*g + rr] * dd[rr];
                *reinterpret_cast<uint2*>(&Xb[col][n0 + 8*g + 4*q]) =
                    make_uint2(pk2(u[0], u[1]), pk2(u[2], u[3]));
            }
        }
        __syncthreads();

        // ===== B2 (MFMA) + B3 fold: u1 = (W2^T u2) ⊙ d1; g[m][c] += u1·W1[n][c]
        {
            short8v w[16];
            LOADW(w, W2Tp);
            f32x16 acc = {};
            MFMA_CHAIN(w, Xb, acc);
            float pg0 = 0.f, pg1 = 0.f, pg2 = 0.f, pg3 = 0.f;
            #pragma unroll
            for (int g = 0; g < 4; ++g) {
                float4 w1v[4];
                #pragma unroll
                for (int rr = 0; rr < 4; ++rr)
                    w1v[rr] = reinterpret_cast<const float4*>(sW1)[n0 + 8*g + 4*q + rr];
                short4 dv = *reinterpret_cast<const short4*>(&D1[col][n0 + 8*g + 4*q]);
                float dd[4] = { b2f((unsigned short)dv.x), b2f((unsigned short)dv.y),
                                b2f((unsigned short)dv.z), b2f((unsigned short)dv.w) };
                #pragma unroll
                for (int rr = 0; rr < 4; ++rr) {
                    float u1 = acc[4*g + rr] * dd[rr];
                    float4 wv4 = w1v[rr];
                    pg0 = fmaf(u1, wv4.x, pg0); pg1 = fmaf(u1, wv4.y, pg1);
                    pg2 = fmaf(u1, wv4.z, pg2); pg3 = fmaf(u1, wv4.w, pg3);
                }
            }
            // combine the two k-halves (q=0,1) within the wave
            pg0 += __shfl_xor(pg0, 32); pg1 += __shfl_xor(pg1, 32);
            pg2 += __shfl_xor(pg2, 32); pg3 += __shfl_xor(pg3, 32);
            if (q == 0)
                *reinterpret_cast<float4*>(&gp[wv][col][0]) =
                    make_float4(pg0, pg1, pg2, pg3);
        }
        __syncthreads();

        // ================= state update (fp32 Verlet + correction)
        if (tid < TB) {
            float g0 = 0.f, g1 = 0.f, g2 = 0.f, g3 = 0.f;
            #pragma unroll
            for (int w = 0; w < 8; ++w) {
                float4 p = *reinterpret_cast<const float4*>(&gp[w][tid][0]);
                g0 += p.x; g1 += p.y; g2 += p.z; g3 += p.w;
            }
            float c0 = g1, c1 = -g0, c2 = g3, c3 = -g2;
            float nrm = sqrtf(c0*c0 + c1*c1 + c2*c2 + c3*c3);
            float ad  = dt * fminf(fmaxf(1.0f - 0.1f * nrm, 0.5f), 1.0f);
            float q1  = sS[tid][0], p1v = sS[tid][1];
            float q2  = sS[tid][2], p2v = sS[tid][3];
            float F1  = -q1 * (1.0f + 2.0f * q2);
            float F2  = -(q2 + q1 * q1 - q2 * q2);
            float p1h = p1v + 0.5f * dt * F1;
            float p2h = p2v + 0.5f * dt * F2;
            float q1n = q1 + dt * p1h;
            float q2n = q2 + dt * p2h;
            float F1n = -q1n * (1.0f + 2.0f * q2n);
            float F2n = -(q2n + q1n * q1n - q2n * q2n);
            float p1n = p1h + 0.5f * dt * F1n;
            float p2n = p2h + 0.5f * dt * F2n;
            float as  = ad * scale;
            float ns0 = q1n + as * c0;
            float ns1 = p1n + as * c1;
            float ns2 = q2n + as * c2;
            float ns3 = p2n + as * c3;
            sS[tid][0] = ns0; sS[tid][1] = ns1; sS[tid][2] = ns2; sS[tid][3] = ns3;
            reinterpret_cast<float4*>(out)[(size_t)(b0 + tid) * NSTEPS + t] =
                make_float4(ns0, ns1, ns2, ns3);
        }
        __syncthreads();
    }
}

extern "C" void kernel_launch(void* const* d_in, const int* in_sizes, int n_in,
                              void* d_out, int out_size, void* d_ws, size_t ws_size,
                              hipStream_t stream) {
    const float* t_eval = (const float*)d_in[0];
    const float* state0 = (const float*)d_in[1];
    const float* W1     = (const float*)d_in[2];
    const float* b1     = (const float*)d_in[3];
    const float* W2     = (const float*)d_in[4];
    const float* b2     = (const float*)d_in[5];
    const float* W3     = (const float*)d_in[6];
    const float* b3     = (const float*)d_in[7];
    const float* W4     = (const float*)d_in[8];
    const float* scale  = (const float*)d_in[10];
    float* out = (float*)d_out;

    unsigned short* wsb = (unsigned short*)d_ws;
    convert_w<<<dim3(256), dim3(256), 0, stream>>>(W2, W3, wsb);

    const short* W2b  = (const short*)(wsb);
    const short* W3b  = (const short*)(wsb + 65536);
    const short* W2Tb = (const short*)(wsb + 131072);
    const short* W3Tb = (const short*)(wsb + 196608);

    const int batch = in_sizes[1] / 4;   // 32768
    sympnet_mfma<<<dim3(batch / TB), dim3(NT), 0, stream>>>(
        t_eval, state0, W1, b1, b2, b3, W4, scale,
        W2b, W3b, W2Tb, W3Tb, out);
}

// Round 9
// 1891.826 us; speedup vs baseline: 1.1436x; 1.1436x over previous
//
#include <hip/hip_runtime.h>
#include <hip/hip_bf16.h>
#include <math.h>

#define H       256
#define TB      64      // samples per workgroup
#define NT      1024    // 16 waves: each owns 16 output rows (16x16x32 MFMA)
#define NSTEPS  32
#define XS      264     // bf16 elems per activation row: 528B (16B-aligned rows)
#define DS1     260     // bf16 elems per d1 row: 520B

typedef __attribute__((ext_vector_type(8))) short short8v;   // 8 bf16 = 4 VGPRs
typedef __attribute__((ext_vector_type(4))) float f32x4;     // 16x16 C/D frag

// tanh via v_exp + v_rcp: ~5 ops, 2 trans.
__device__ __forceinline__ float fast_tanh(float x) {
    float e;
    asm("v_exp_f32 %0, %1" : "=v"(e) : "v"(x * 2.8853900817779268f)); // 2^(2x*log2e)
    return fmaf(-2.0f, __builtin_amdgcn_rcpf(e + 1.0f), 1.0f);
}

// pack 2 fp32 -> 1 u32 of 2 bf16, RNE (v_cvt_pk_bf16_f32)
__device__ __forceinline__ unsigned pk2(float lo, float hi) {
    __hip_bfloat162 h2 = __float22bfloat162_rn(make_float2(lo, hi));
    unsigned u; __builtin_memcpy(&u, &h2, 4);
    return u;
}
__device__ __forceinline__ unsigned short f2b(float x) {
    unsigned u = __float_as_uint(x);
    u += 0x7FFFu + ((u >> 16) & 1u);
    return (unsigned short)(u >> 16);
}
__device__ __forceinline__ float b2f(unsigned short h) {
    return __uint_as_float(((unsigned)h) << 16);
}

// ---- pre-pass: fp32 W2,W3 -> bf16 row-major + transposed copies in d_ws ----
__global__ void convert_w(const float* __restrict__ W2, const float* __restrict__ W3,
                          unsigned short* __restrict__ wsb) {
    int t = blockIdx.x * blockDim.x + threadIdx.x;   // 0..65535
    int i = t >> 8, j = t & 255;
    float w2 = W2[t], w3 = W3[t];
    wsb[t]                         = f2b(w2);
    wsb[65536 + t]                 = f2b(w3);
    wsb[131072 + (j << 8) + i]     = f2b(w2);   // W2T[j][i] = W2[i][j]
    wsb[196608 + (j << 8) + i]     = f2b(w3);
}

// prefetch one 16x256 weight panel slice (8 x 16B) into registers, pinned at
// the top of the phase (round-2/3 proven pattern: issue early, barrier-drain
// at phase end gives a full phase of latency cover).
#define PREFETCH_W(dst, base)                                                  \
    _Pragma("unroll")                                                          \
    for (int kc = 0; kc < 8; ++kc)                                             \
        dst[kc] = *reinterpret_cast<const short8v*>((base) + kc * 32);         \
    __builtin_amdgcn_sched_barrier(0);

// 4 independent MFMA chains (one per 16-sample tile), K=256 in 8 steps of 32.
// A = weight frags (regs), B = activations (LDS).
#define MFMA_CHAIN(WREG, XSRC)                                                 \
    _Pragma("unroll")                                                          \
    for (int kc = 0; kc < 8; ++kc) {                                           \
        short8v b0 = *reinterpret_cast<const short8v*>(&XSRC[sl][kc*32 + kg*8]);      \
        short8v b1 = *reinterpret_cast<const short8v*>(&XSRC[16 + sl][kc*32 + kg*8]); \
        short8v b2v = *reinterpret_cast<const short8v*>(&XSRC[32 + sl][kc*32 + kg*8]);\
        short8v b3v = *reinterpret_cast<const short8v*>(&XSRC[48 + sl][kc*32 + kg*8]);\
        acc0 = __builtin_amdgcn_mfma_f32_16x16x32_bf16(WREG[kc], b0,  acc0, 0, 0, 0); \
        acc1 = __builtin_amdgcn_mfma_f32_16x16x32_bf16(WREG[kc], b1,  acc1, 0, 0, 0); \
        acc2 = __builtin_amdgcn_mfma_f32_16x16x32_bf16(WREG[kc], b2v, acc2, 0, 0, 0); \
        acc3 = __builtin_amdgcn_mfma_f32_16x16x32_bf16(WREG[kc], b3v, acc3, 0, 0, 0); \
    }

__global__ __attribute__((amdgpu_flat_work_group_size(NT, NT),
                          amdgpu_waves_per_eu(4, 4)))   // pin the 128-VGPR tier
void sympnet_mfma(const float* __restrict__ t_eval,
                  const float* __restrict__ state0,
                  const float* __restrict__ W1, const float* __restrict__ b1,
                  const float* __restrict__ b2, const float* __restrict__ b3,
                  const float* __restrict__ W4, const float* __restrict__ scale_p,
                  const short* __restrict__ W2b,  const short* __restrict__ W3b,
                  const short* __restrict__ W2Tb, const short* __restrict__ W3Tb,
                  float* __restrict__ out)
{
    __shared__ unsigned short Xa[TB][XS];
    __shared__ unsigned short Xb[TB][XS];
    __shared__ unsigned short D1[TB][DS1];   // (1 - h1^2) bf16
    __shared__ float sS[TB][4];
    __shared__ float gp[16][TB][4];          // per-wave gradient partials
    __shared__ float sW1[H * 4];             // W1 rows (float4 each), L1 + B2 fold
    __shared__ float sB1[H], sB2[H], sB3[H], sW4[H];

    const int tid  = threadIdx.x;
    const int lane = tid & 63;
    const int wv   = tid >> 6;      // wave 0..15
    const int sl   = lane & 15;     // A-row-in-tile / B,C sample index
    const int kg   = lane >> 4;     // k-group 0..3 (8 elems each) / C row-group
    const int n0   = wv * 16;       // this wave's 16 output rows for every GEMM

    const float dt    = t_eval[1] - t_eval[0];
    const float scale = scale_p[0];
    const int   b0    = blockIdx.x * TB;

    // per-wave weight row base pointers (row n0+sl, k-slice kg*8)
    const short* W2p  = W2b  + ((n0 + sl) << 8) + kg * 8;
    const short* W3p  = W3b  + ((n0 + sl) << 8) + kg * 8;
    const short* W3Tp = W3Tb + ((n0 + sl) << 8) + kg * 8;
    const short* W2Tp = W2Tb + ((n0 + sl) << 8) + kg * 8;

    // register double-buffer for weight fragments (8 frags = 32 VGPRs each)
    short8v wA[8], wB[8];
    PREFETCH_W(wA, W2p);            // W2 for the first L2 phase

    if (tid < H) {
        reinterpret_cast<float4*>(sW1)[tid] = reinterpret_cast<const float4*>(W1)[tid];
        sB1[tid] = b1[tid];
        sB2[tid] = b2[tid];
        sB3[tid] = b3[tid];
        sW4[tid] = W4[tid];
    }
    if (tid < TB) {
        float4 s = reinterpret_cast<const float4*>(state0)[b0 + tid];
        sS[tid][0] = s.x; sS[tid][1] = s.y; sS[tid][2] = s.z; sS[tid][3] = s.w;
        reinterpret_cast<float4*>(out)[(size_t)(b0 + tid) * NSTEPS] = s;
    }
    __syncthreads();

    unsigned d2p[8];   // (1 - h2^2), 4 tiles x 4 vals, packed bf16 pairs

    for (int t = 1; t < NSTEPS; ++t) {
        // ================= L1 (VALU): h1 = tanh(s @ W1^T + b1) -> Xa, D1
        {
            const int j0 = (tid & 31) * 8;        // 32 dim-groups of 8
            const int r0 = (tid >> 5) * 2;        // 32 slots x 2 rows = 64 samples
            float4 wvv[8];
            #pragma unroll
            for (int jj = 0; jj < 8; ++jj)
                wvv[jj] = reinterpret_cast<const float4*>(sW1)[j0 + jj];
            float bb[8];
            #pragma unroll
            for (int jj = 0; jj < 8; ++jj) bb[jj] = sB1[j0 + jj];
            #pragma unroll
            for (int ii = 0; ii < 2; ++ii) {
                float4 sv = *reinterpret_cast<const float4*>(&sS[r0 + ii][0]);
                float h[8], d[8];
                #pragma unroll
                for (int jj = 0; jj < 8; ++jj) {
                    float z = bb[jj] + sv.x * wvv[jj].x + sv.y * wvv[jj].y
                                     + sv.z * wvv[jj].z + sv.w * wvv[jj].w;
                    h[jj] = fast_tanh(z);
                    d[jj] = fmaf(-h[jj], h[jj], 1.0f);
                }
                *reinterpret_cast<uint2*>(&Xa[r0 + ii][j0]) =
                    make_uint2(pk2(h[0], h[1]), pk2(h[2], h[3]));
                *reinterpret_cast<uint2*>(&Xa[r0 + ii][j0 + 4]) =
                    make_uint2(pk2(h[4], h[5]), pk2(h[6], h[7]));
                *reinterpret_cast<uint2*>(&D1[r0 + ii][j0]) =
                    make_uint2(pk2(d[0], d[1]), pk2(d[2], d[3]));
                *reinterpret_cast<uint2*>(&D1[r0 + ii][j0 + 4]) =
                    make_uint2(pk2(d[4], d[5]), pk2(d[6], d[7]));
            }
        }
        __syncthreads();

        // ================= L2 (MFMA): h2 = tanh(W2 h1 + b2) -> Xb, d2p regs
        {
            PREFETCH_W(wB, W3p);                 // cover W3 under this phase
            f32x4 acc0 = {}, acc1 = {}, acc2 = {}, acc3 = {};
            MFMA_CHAIN(wA, Xa);
            float4 bv = *reinterpret_cast<const float4*>(&sB2[n0 + kg * 4]);
            const float* bp = reinterpret_cast<const float*>(&bv);
            #pragma unroll
            for (int mt = 0; mt < 4; ++mt) {
                f32x4 acc = (mt == 0) ? acc0 : (mt == 1) ? acc1 : (mt == 2) ? acc2 : acc3;
                float h[4], d[4];
                #pragma unroll
                for (int rr = 0; rr < 4; ++rr) {
                    h[rr] = fast_tanh(acc[rr] + bp[rr]);
                    d[rr] = fmaf(-h[rr], h[rr], 1.0f);
                }
                d2p[mt*2]     = pk2(d[0], d[1]);
                d2p[mt*2 + 1] = pk2(d[2], d[3]);
                *reinterpret_cast<uint2*>(&Xb[mt*16 + sl][n0 + kg*4]) =
                    make_uint2(pk2(h[0], h[1]), pk2(h[2], h[3]));
            }
        }
        __syncthreads();

        // ================= L3 (MFMA): u3 = W4 ⊙ (1 - tanh^2(W3 h2 + b3)) -> Xa
        {
            PREFETCH_W(wA, W3Tp);                // cover W3^T
            f32x4 acc0 = {}, acc1 = {}, acc2 = {}, acc3 = {};
            MFMA_CHAIN(wB, Xb);
            float4 bv  = *reinterpret_cast<const float4*>(&sB3[n0 + kg * 4]);
            float4 wv4 = *reinterpret_cast<const float4*>(&sW4[n0 + kg * 4]);
            const float* bp = reinterpret_cast<const float*>(&bv);
            const float* wp = reinterpret_cast<const float*>(&wv4);
            #pragma unroll
            for (int mt = 0; mt < 4; ++mt) {
                f32x4 acc = (mt == 0) ? acc0 : (mt == 1) ? acc1 : (mt == 2) ? acc2 : acc3;
                float u[4];
                #pragma unroll
                for (int rr = 0; rr < 4; ++rr) {
                    float h = fast_tanh(acc[rr] + bp[rr]);
                    u[rr] = wp[rr] * fmaf(-h, h, 1.0f);
                }
                *reinterpret_cast<uint2*>(&Xa[mt*16 + sl][n0 + kg*4]) =
                    make_uint2(pk2(u[0], u[1]), pk2(u[2], u[3]));
            }
        }
        __syncthreads();

        // ================= B1 (MFMA): u2 = (W3^T u3) ⊙ d2 -> Xb
        {
            PREFETCH_W(wB, W2Tp);                // cover W2^T
            f32x4 acc0 = {}, acc1 = {}, acc2 = {}, acc3 = {};
            MFMA_CHAIN(wA, Xa);
            #pragma unroll
            for (int mt = 0; mt < 4; ++mt) {
                f32x4 acc = (mt == 0) ? acc0 : (mt == 1) ? acc1 : (mt == 2) ? acc2 : acc3;
                float dd[4] = { b2f((unsigned short)(d2p[mt*2]   & 0xffffu)),
                                b2f((unsigned short)(d2p[mt*2]   >> 16)),
                                b2f((unsigned short)(d2p[mt*2+1] & 0xffffu)),
                                b2f((unsigned short)(d2p[mt*2+1] >> 16)) };
                float u[4];
                #pragma unroll
                for (int rr = 0; rr < 4; ++rr)
                    u[rr] = acc[rr] * dd[rr];
                *reinterpret_cast<uint2*>(&Xb[mt*16 + sl][n0 + kg*4]) =
                    make_uint2(pk2(u[0], u[1]), pk2(u[2], u[3]));
            }
        }
        __syncthreads();

        // ===== B2 (MFMA) + B3 fold: u1 = (W2^T u2) ⊙ d1; g[m][c] += u1·W1[n][c]
        {
            PREFETCH_W(wA, W2p);                 // next step's W2 (covered by fold+update+L1)
            f32x4 acc0 = {}, acc1 = {}, acc2 = {}, acc3 = {};
            MFMA_CHAIN(wB, Xb);
            float4 w1v[4];
            #pragma unroll
            for (int rr = 0; rr < 4; ++rr)
                w1v[rr] = reinterpret_cast<const float4*>(sW1)[n0 + kg*4 + rr];
            #pragma unroll
            for (int mt = 0; mt < 4; ++mt) {
                f32x4 acc = (mt == 0) ? acc0 : (mt == 1) ? acc1 : (mt == 2) ? acc2 : acc3;
                short4 dv = *reinterpret_cast<const short4*>(&D1[mt*16 + sl][n0 + kg*4]);
                float dd[4] = { b2f((unsigned short)dv.x), b2f((unsigned short)dv.y),
                                b2f((unsigned short)dv.z), b2f((unsigned short)dv.w) };
                float pg0 = 0.f, pg1 = 0.f, pg2 = 0.f, pg3 = 0.f;
                #pragma unroll
                for (int rr = 0; rr < 4; ++rr) {
                    float u1 = acc[rr] * dd[rr];
                    float4 w = w1v[rr];
                    pg0 = fmaf(u1, w.x, pg0); pg1 = fmaf(u1, w.y, pg1);
                    pg2 = fmaf(u1, w.z, pg2); pg3 = fmaf(u1, w.w, pg3);
                }
                // combine the 4 k-quarters (kg=0..3) within the wave
                pg0 += __shfl_xor(pg0, 16); pg1 += __shfl_xor(pg1, 16);
                pg2 += __shfl_xor(pg2, 16); pg3 += __shfl_xor(pg3, 16);
                pg0 += __shfl_xor(pg0, 32); pg1 += __shfl_xor(pg1, 32);
                pg2 += __shfl_xor(pg2, 32); pg3 += __shfl_xor(pg3, 32);
                if (kg == 0)
                    *reinterpret_cast<float4*>(&gp[wv][mt*16 + sl][0]) =
                        make_float4(pg0, pg1, pg2, pg3);
            }
        }
        __syncthreads();

        // ================= state update (fp32 Verlet + correction)
        if (tid < TB) {
            float g0 = 0.f, g1 = 0.f, g2 = 0.f, g3 = 0.f;
            #pragma unroll
            for (int w = 0; w < 16; ++w) {
                float4 p = *reinterpret_cast<const float4*>(&gp[w][tid][0]);
                g0 += p.x; g1 += p.y; g2 += p.z; g3 += p.w;
            }
            float c0 = g1, c1 = -g0, c2 = g3, c3 = -g2;
            float nrm = sqrtf(c0*c0 + c1*c1 + c2*c2 + c3*c3);
            float ad  = dt * fminf(fmaxf(1.0f - 0.1f * nrm, 0.5f), 1.0f);
            float q1  = sS[tid][0], p1v = sS[tid][1];
            float q2  = sS[tid][2], p2v = sS[tid][3];
            float F1  = -q1 * (1.0f + 2.0f * q2);
            float F2  = -(q2 + q1 * q1 - q2 * q2);
            float p1h = p1v + 0.5f * dt * F1;
            float p2h = p2v + 0.5f * dt * F2;
            float q1n = q1 + dt * p1h;
            float q2n = q2 + dt * p2h;
            float F1n = -q1n * (1.0f + 2.0f * q2n);
            float F2n = -(q2n + q1n * q1n - q2n * q2n);
            float p1n = p1h + 0.5f * dt * F1n;
            float p2n = p2h + 0.5f * dt * F2n;
            float as  = ad * scale;
            float ns0 = q1n + as * c0;
            float ns1 = p1n + as * c1;
            float ns2 = q2n + as * c2;
            float ns3 = p2n + as * c3;
            sS[tid][0] = ns0; sS[tid][1] = ns1; sS[tid][2] = ns2; sS[tid][3] = ns3;
            reinterpret_cast<float4*>(out)[(size_t)(b0 + tid) * NSTEPS + t] =
                make_float4(ns0, ns1, ns2, ns3);
        }
        __syncthreads();
    }
}

extern "C" void kernel_launch(void* const* d_in, const int* in_sizes, int n_in,
                              void* d_out, int out_size, void* d_ws, size_t ws_size,
                              hipStream_t stream) {
    const float* t_eval = (const float*)d_in[0];
    const float* state0 = (const float*)d_in[1];
    const float* W1     = (const float*)d_in[2];
    const float* b1     = (const float*)d_in[3];
    const float* W2     = (const float*)d_in[4];
    const float* b2     = (const float*)d_in[5];
    const float* W3     = (const float*)d_in[6];
    const float* b3     = (const float*)d_in[7];
    const float* W4     = (const float*)d_in[8];
    const float* scale  = (const float*)d_in[10];
    float* out = (float*)d_out;

    unsigned short* wsb = (unsigned short*)d_ws;
    convert_w<<<dim3(256), dim3(256), 0, stream>>>(W2, W3, wsb);

    const short* W2b  = (const short*)(wsb);
    const short* W3b  = (const short*)(wsb + 65536);
    const short* W2Tb = (const short*)(wsb + 131072);
    const short* W3Tb = (const short*)(wsb + 196608);

    const int batch = in_sizes[1] / 4;   // 32768
    sympnet_mfma<<<dim3(batch / TB), dim3(NT), 0, stream>>>(
        t_eval, state0, W1, b1, b2, b3, W4, scale,
        W2b, W3b, W2Tb, W3Tb, out);
}

// Round 10
// 1503.425 us; speedup vs baseline: 1.4390x; 1.2583x over previous
//
#include <hip/hip_runtime.h>
#include <hip/hip_bf16.h>
#include <math.h>

#define H       256
#define TB      64      // samples per workgroup
#define NT      1024    // 16 waves: each owns 16 output rows (16x16x32 MFMA)
#define NSTEPS  32
#define XS      264     // bf16 elems per activation row: 528B (16B-aligned rows)
#define DS1     260     // bf16 elems per d1 row: 520B

typedef __attribute__((ext_vector_type(8))) short short8v;   // 8 bf16 = 4 VGPRs
typedef __attribute__((ext_vector_type(4))) float f32x4;     // 16x16 C/D frag

// tanh via v_exp + v_rcp: ~5 ops, 2 trans.
__device__ __forceinline__ float fast_tanh(float x) {
    float e;
    asm("v_exp_f32 %0, %1" : "=v"(e) : "v"(x * 2.8853900817779268f)); // 2^(2x*log2e)
    return fmaf(-2.0f, __builtin_amdgcn_rcpf(e + 1.0f), 1.0f);
}

// pack 2 fp32 -> 1 u32 of 2 bf16, RNE (v_cvt_pk_bf16_f32)
__device__ __forceinline__ unsigned pk2(float lo, float hi) {
    __hip_bfloat162 h2 = __float22bfloat162_rn(make_float2(lo, hi));
    unsigned u; __builtin_memcpy(&u, &h2, 4);
    return u;
}
__device__ __forceinline__ unsigned short f2b(float x) {
    unsigned u = __float_as_uint(x);
    u += 0x7FFFu + ((u >> 16) & 1u);
    return (unsigned short)(u >> 16);
}
__device__ __forceinline__ float b2f(unsigned short h) {
    return __uint_as_float(((unsigned)h) << 16);
}

// ---- pre-pass: fp32 W2,W3 -> bf16 row-major + transposed copies in d_ws ----
__global__ void convert_w(const float* __restrict__ W2, const float* __restrict__ W3,
                          unsigned short* __restrict__ wsb) {
    int t = blockIdx.x * blockDim.x + threadIdx.x;   // 0..65535
    int i = t >> 8, j = t & 255;
    float w2 = W2[t], w3 = W3[t];
    wsb[t]                         = f2b(w2);
    wsb[65536 + t]                 = f2b(w3);
    wsb[131072 + (j << 8) + i]     = f2b(w2);   // W2T[j][i] = W2[i][j]
    wsb[196608 + (j << 8) + i]     = f2b(w3);
}

// ---- forced register burst: 8 x global_load_dwordx4 (one 16x256 panel slice,
// row n0+sl, k-slice kg*8; frag kc at byte offset kc*64). asm tuple outputs
// cannot be split/sunk/rematerialized (round-7-proven: burst issues together,
// no spill). vmcnt(0)+sched_barrier fences the MFMA chain (rule #18).
#define GLW(dst, base, OFFB)                                                   \
    asm volatile("global_load_dwordx4 %0, %1, off offset:" #OFFB               \
                 : "=v"(dst) : "v"(base));
#define LOADW(w, base)                                                         \
    GLW(w[0], base, 0)   GLW(w[1], base, 64)  GLW(w[2], base, 128)             \
    GLW(w[3], base, 192) GLW(w[4], base, 256) GLW(w[5], base, 320)             \
    GLW(w[6], base, 384) GLW(w[7], base, 448)                                  \
    asm volatile("s_waitcnt vmcnt(0)" ::: "memory");                           \
    __builtin_amdgcn_sched_barrier(0);

// 4 independent MFMA chains (one per 16-sample tile), K=256 in 8 steps of 32.
// A = weight frags (regs), B = activations (LDS).
#define MFMA_CHAIN(WREG, XSRC)                                                 \
    _Pragma("unroll")                                                          \
    for (int kc = 0; kc < 8; ++kc) {                                           \
        short8v b0 = *reinterpret_cast<const short8v*>(&XSRC[sl][kc*32 + kg*8]);      \
        short8v b1 = *reinterpret_cast<const short8v*>(&XSRC[16 + sl][kc*32 + kg*8]); \
        short8v b2v = *reinterpret_cast<const short8v*>(&XSRC[32 + sl][kc*32 + kg*8]);\
        short8v b3v = *reinterpret_cast<const short8v*>(&XSRC[48 + sl][kc*32 + kg*8]);\
        acc0 = __builtin_amdgcn_mfma_f32_16x16x32_bf16(WREG[kc], b0,  acc0, 0, 0, 0); \
        acc1 = __builtin_amdgcn_mfma_f32_16x16x32_bf16(WREG[kc], b1,  acc1, 0, 0, 0); \
        acc2 = __builtin_amdgcn_mfma_f32_16x16x32_bf16(WREG[kc], b2v, acc2, 0, 0, 0); \
        acc3 = __builtin_amdgcn_mfma_f32_16x16x32_bf16(WREG[kc], b3v, acc3, 0, 0, 0); \
    }

__global__ __launch_bounds__(NT)
void sympnet_mfma(const float* __restrict__ t_eval,
                  const float* __restrict__ state0,
                  const float* __restrict__ W1, const float* __restrict__ b1,
                  const float* __restrict__ b2, const float* __restrict__ b3,
                  const float* __restrict__ W4, const float* __restrict__ scale_p,
                  const short* __restrict__ W2b,  const short* __restrict__ W3b,
                  const short* __restrict__ W2Tb, const short* __restrict__ W3Tb,
                  float* __restrict__ out)
{
    __shared__ unsigned short Xa[TB][XS];
    __shared__ unsigned short Xb[TB][XS];
    __shared__ unsigned short D1[TB][DS1];   // (1 - h1^2) bf16
    __shared__ float sS[TB][4];
    __shared__ float gp[16][TB][4];          // per-wave gradient partials
    __shared__ float sW1[H * 4];             // W1 rows (float4 each), L1 + B2 fold
    __shared__ float sB1[H], sB2[H], sB3[H], sW4[H];

    const int tid  = threadIdx.x;
    const int lane = tid & 63;
    const int wv   = tid >> 6;      // wave 0..15
    const int sl   = lane & 15;     // A-row-in-tile / B,C sample index
    const int kg   = lane >> 4;     // k-group 0..3 (8 elems each) / C row-group
    const int n0   = wv * 16;       // this wave's 16 output rows for every GEMM

    const float dt    = t_eval[1] - t_eval[0];
    const float scale = scale_p[0];
    const int   b0    = blockIdx.x * TB;

    // per-wave weight row base pointers (row n0+sl, k-slice kg*8)
    const short* W2p  = W2b  + ((n0 + sl) << 8) + kg * 8;
    const short* W3p  = W3b  + ((n0 + sl) << 8) + kg * 8;
    const short* W3Tp = W3Tb + ((n0 + sl) << 8) + kg * 8;
    const short* W2Tp = W2Tb + ((n0 + sl) << 8) + kg * 8;

    if (tid < H) {
        reinterpret_cast<float4*>(sW1)[tid] = reinterpret_cast<const float4*>(W1)[tid];
        sB1[tid] = b1[tid];
        sB2[tid] = b2[tid];
        sB3[tid] = b3[tid];
        sW4[tid] = W4[tid];
    }
    if (tid < TB) {
        float4 s = reinterpret_cast<const float4*>(state0)[b0 + tid];
        sS[tid][0] = s.x; sS[tid][1] = s.y; sS[tid][2] = s.z; sS[tid][3] = s.w;
        reinterpret_cast<float4*>(out)[(size_t)(b0 + tid) * NSTEPS] = s;
    }
    __syncthreads();

    unsigned d2p[8];   // (1 - h2^2), 4 tiles x 4 vals, packed bf16 pairs

    for (int t = 1; t < NSTEPS; ++t) {
        // ================= L1 (VALU): h1 = tanh(s @ W1^T + b1) -> Xa, D1
        {
            const int j0 = (tid & 31) * 8;        // 32 dim-groups of 8
            const int r0 = (tid >> 5) * 2;        // 32 slots x 2 rows = 64 samples
            float4 wvv[8];
            #pragma unroll
            for (int jj = 0; jj < 8; ++jj)
                wvv[jj] = reinterpret_cast<const float4*>(sW1)[j0 + jj];
            float bb[8];
            #pragma unroll
            for (int jj = 0; jj < 8; ++jj) bb[jj] = sB1[j0 + jj];
            #pragma unroll
            for (int ii = 0; ii < 2; ++ii) {
                float4 sv = *reinterpret_cast<const float4*>(&sS[r0 + ii][0]);
                float h[8], d[8];
                #pragma unroll
                for (int jj = 0; jj < 8; ++jj) {
                    float z = bb[jj] + sv.x * wvv[jj].x + sv.y * wvv[jj].y
                                     + sv.z * wvv[jj].z + sv.w * wvv[jj].w;
                    h[jj] = fast_tanh(z);
                    d[jj] = fmaf(-h[jj], h[jj], 1.0f);
                }
                *reinterpret_cast<uint2*>(&Xa[r0 + ii][j0]) =
                    make_uint2(pk2(h[0], h[1]), pk2(h[2], h[3]));
                *reinterpret_cast<uint2*>(&Xa[r0 + ii][j0 + 4]) =
                    make_uint2(pk2(h[4], h[5]), pk2(h[6], h[7]));
                *reinterpret_cast<uint2*>(&D1[r0 + ii][j0]) =
                    make_uint2(pk2(d[0], d[1]), pk2(d[2], d[3]));
                *reinterpret_cast<uint2*>(&D1[r0 + ii][j0 + 4]) =
                    make_uint2(pk2(d[4], d[5]), pk2(d[6], d[7]));
            }
        }
        __syncthreads();

        // ================= L2 (MFMA): h2 = tanh(W2 h1 + b2) -> Xb, d2p regs
        {
            short8v w[8];
            LOADW(w, W2p);
            f32x4 acc0 = {}, acc1 = {}, acc2 = {}, acc3 = {};
            MFMA_CHAIN(w, Xa);
            float4 bv = *reinterpret_cast<const float4*>(&sB2[n0 + kg * 4]);
            const float* bp = reinterpret_cast<const float*>(&bv);
            #pragma unroll
            for (int mt = 0; mt < 4; ++mt) {
                f32x4 acc = (mt == 0) ? acc0 : (mt == 1) ? acc1 : (mt == 2) ? acc2 : acc3;
                float h[4], d[4];
                #pragma unroll
                for (int rr = 0; rr < 4; ++rr) {
                    h[rr] = fast_tanh(acc[rr] + bp[rr]);
                    d[rr] = fmaf(-h[rr], h[rr], 1.0f);
                }
                d2p[mt*2]     = pk2(d[0], d[1]);
                d2p[mt*2 + 1] = pk2(d[2], d[3]);
                *reinterpret_cast<uint2*>(&Xb[mt*16 + sl][n0 + kg*4]) =
                    make_uint2(pk2(h[0], h[1]), pk2(h[2], h[3]));
            }
        }
        __syncthreads();

        // ================= L3 (MFMA): u3 = W4 ⊙ (1 - tanh^2(W3 h2 + b3)) -> Xa
        {
            short8v w[8];
            LOADW(w, W3p);
            f32x4 acc0 = {}, acc1 = {}, acc2 = {}, acc3 = {};
            MFMA_CHAIN(w, Xb);
            float4 bv  = *reinterpret_cast<const float4*>(&sB3[n0 + kg * 4]);
            float4 wv4 = *reinterpret_cast<const float4*>(&sW4[n0 + kg * 4]);
            const float* bp = reinterpret_cast<const float*>(&bv);
            const float* wp = reinterpret_cast<const float*>(&wv4);
            #pragma unroll
            for (int mt = 0; mt < 4; ++mt) {
                f32x4 acc = (mt == 0) ? acc0 : (mt == 1) ? acc1 : (mt == 2) ? acc2 : acc3;
                float u[4];
                #pragma unroll
                for (int rr = 0; rr < 4; ++rr) {
                    float h = fast_tanh(acc[rr] + bp[rr]);
                    u[rr] = wp[rr] * fmaf(-h, h, 1.0f);
                }
                *reinterpret_cast<uint2*>(&Xa[mt*16 + sl][n0 + kg*4]) =
                    make_uint2(pk2(u[0], u[1]), pk2(u[2], u[3]));
            }
        }
        __syncthreads();

        // ================= B1 (MFMA): u2 = (W3^T u3) ⊙ d2 -> Xb
        {
            short8v w[8];
            LOADW(w, W3Tp);
            f32x4 acc0 = {}, acc1 = {}, acc2 = {}, acc3 = {};
            MFMA_CHAIN(w, Xa);
            #pragma unroll
            for (int mt = 0; mt < 4; ++mt) {
                f32x4 acc = (mt == 0) ? acc0 : (mt == 1) ? acc1 : (mt == 2) ? acc2 : acc3;
                float dd[4] = { b2f((unsigned short)(d2p[mt*2]   & 0xffffu)),
                                b2f((unsigned short)(d2p[mt*2]   >> 16)),
                                b2f((unsigned short)(d2p[mt*2+1] & 0xffffu)),
                                b2f((unsigned short)(d2p[mt*2+1] >> 16)) };
                float u[4];
                #pragma unroll
                for (int rr = 0; rr < 4; ++rr)
                    u[rr] = acc[rr] * dd[rr];
                *reinterpret_cast<uint2*>(&Xb[mt*16 + sl][n0 + kg*4]) =
                    make_uint2(pk2(u[0], u[1]), pk2(u[2], u[3]));
            }
        }
        __syncthreads();

        // ===== B2 (MFMA) + B3 fold: u1 = (W2^T u2) ⊙ d1; g[m][c] += u1·W1[n][c]
        {
            short8v w[8];
            LOADW(w, W2Tp);
            f32x4 acc0 = {}, acc1 = {}, acc2 = {}, acc3 = {};
            MFMA_CHAIN(w, Xb);
            float4 w1v[4];
            #pragma unroll
            for (int rr = 0; rr < 4; ++rr)
                w1v[rr] = reinterpret_cast<const float4*>(sW1)[n0 + kg*4 + rr];
            #pragma unroll
            for (int mt = 0; mt < 4; ++mt) {
                f32x4 acc = (mt == 0) ? acc0 : (mt == 1) ? acc1 : (mt == 2) ? acc2 : acc3;
                short4 dv = *reinterpret_cast<const short4*>(&D1[mt*16 + sl][n0 + kg*4]);
                float dd[4] = { b2f((unsigned short)dv.x), b2f((unsigned short)dv.y),
                                b2f((unsigned short)dv.z), b2f((unsigned short)dv.w) };
                float pg0 = 0.f, pg1 = 0.f, pg2 = 0.f, pg3 = 0.f;
                #pragma unroll
                for (int rr = 0; rr < 4; ++rr) {
                    float u1 = acc[rr] * dd[rr];
                    float4 w = w1v[rr];
                    pg0 = fmaf(u1, w.x, pg0); pg1 = fmaf(u1, w.y, pg1);
                    pg2 = fmaf(u1, w.z, pg2); pg3 = fmaf(u1, w.w, pg3);
                }
                // combine the 4 k-quarters (kg=0..3) within the wave
                pg0 += __shfl_xor(pg0, 16); pg1 += __shfl_xor(pg1, 16);
                pg2 += __shfl_xor(pg2, 16); pg3 += __shfl_xor(pg3, 16);
                pg0 += __shfl_xor(pg0, 32); pg1 += __shfl_xor(pg1, 32);
                pg2 += __shfl_xor(pg2, 32); pg3 += __shfl_xor(pg3, 32);
                if (kg == 0)
                    *reinterpret_cast<float4*>(&gp[wv][mt*16 + sl][0]) =
                        make_float4(pg0, pg1, pg2, pg3);
            }
        }
        __syncthreads();

        // ================= state update (fp32 Verlet + correction)
        if (tid < TB) {
            float g0 = 0.f, g1 = 0.f, g2 = 0.f, g3 = 0.f;
            #pragma unroll
            for (int w = 0; w < 16; ++w) {
                float4 p = *reinterpret_cast<const float4*>(&gp[w][tid][0]);
                g0 += p.x; g1 += p.y; g2 += p.z; g3 += p.w;
            }
            float c0 = g1, c1 = -g0, c2 = g3, c3 = -g2;
            float nrm = sqrtf(c0*c0 + c1*c1 + c2*c2 + c3*c3);
            float ad  = dt * fminf(fmaxf(1.0f - 0.1f * nrm, 0.5f), 1.0f);
            float q1  = sS[tid][0], p1v = sS[tid][1];
            float q2  = sS[tid][2], p2v = sS[tid][3];
            float F1  = -q1 * (1.0f + 2.0f * q2);
            float F2  = -(q2 + q1 * q1 - q2 * q2);
            float p1h = p1v + 0.5f * dt * F1;
            float p2h = p2v + 0.5f * dt * F2;
            float q1n = q1 + dt * p1h;
            float q2n = q2 + dt * p2h;
            float F1n = -q1n * (1.0f + 2.0f * q2n);
            float F2n = -(q2n + q1n * q1n - q2n * q2n);
            float p1n = p1h + 0.5f * dt * F1n;
            float p2n = p2h + 0.5f * dt * F2n;
            float as  = ad * scale;
            float ns0 = q1n + as * c0;
            float ns1 = p1n + as * c1;
            float ns2 = q2n + as * c2;
            float ns3 = p2n + as * c3;
            sS[tid][0] = ns0; sS[tid][1] = ns1; sS[tid][2] = ns2; sS[tid][3] = ns3;
            reinterpret_cast<float4*>(out)[(size_t)(b0 + tid) * NSTEPS + t] =
                make_float4(ns0, ns1, ns2, ns3);
        }
        __syncthreads();
    }
}

extern "C" void kernel_launch(void* const* d_in, const int* in_sizes, int n_in,
                              void* d_out, int out_size, void* d_ws, size_t ws_size,
                              hipStream_t stream) {
    const float* t_eval = (const float*)d_in[0];
    const float* state0 = (const float*)d_in[1];
    const float* W1     = (const float*)d_in[2];
    const float* b1     = (const float*)d_in[3];
    const float* W2     = (const float*)d_in[4];
    const float* b2     = (const float*)d_in[5];
    const float* W3     = (const float*)d_in[6];
    const float* b3     = (const float*)d_in[7];
    const float* W4     = (const float*)d_in[8];
    const float* scale  = (const float*)d_in[10];
    float* out = (float*)d_out;

    unsigned short* wsb = (unsigned short*)d_ws;
    convert_w<<<dim3(256), dim3(256), 0, stream>>>(W2, W3, wsb);

    const short* W2b  = (const short*)(wsb);
    const short* W3b  = (const short*)(wsb + 65536);
    const short* W2Tb = (const short*)(wsb + 131072);
    const short* W3Tb = (const short*)(wsb + 196608);

    const int batch = in_sizes[1] / 4;   // 32768
    sympnet_mfma<<<dim3(batch / TB), dim3(NT), 0, stream>>>(
        t_eval, state0, W1, b1, b2, b3, W4, scale,
        W2b, W3b, W2Tb, W3Tb, out);
}